// Round 16
// baseline (189127.893 us; speedup 1.0000x reference)
//
#include <hip/hip_runtime.h>
#include <hip/hip_bf16.h>
#include <math.h>

// ---------------------------------------------------------------------------
// FasterRCNN RPN — np-gold f32 BLAS-mimicry ticket #1.
// conv: im2col semantics, k = c*9+tap ascending, OpenBLAS sgemm rounding
//   model: seq-FMA within kc=384 chunks, chunk sums added in order (48 chunks).
// head: k=512 -> chunks 384+128, same rule.
// Downstream: strict f32 (contract off), f32-score sort keys w/ index ties,
// strict f32 IOU/NMS, f32 output.
//
// Workspace (bytes):
//   h      [2500][512]   f32 (per-image)   0 .. 5,120,000
//   scores [4][22500]    f32               .. 5,480,000
//   boxes  [4][22500][4] f32               .. 6,920,000
//   keys   [4][32768]    u64               .. 7,968,576
// ---------------------------------------------------------------------------

#define CIN   2048
#define CH    512
#define NPOS  2500
#define NANCH 22500
#define NSORT 32768
#define BIMG  4
#define PRE_NMS_K 2000
#define TOP_N 1000

__device__ __forceinline__ float read_dimf(const void* p) {
    int i32 = *(const int*)p;
    if (i32 >= 1 && i32 <= 1000000) return (float)i32;
    float f32 = *(const float*)p;
    if (f32 >= 1.f && f32 <= 1e6f) return f32;
    return (float)(*(const double*)p);
}

// -------- K1: f32 conv, k=(c*9+tap) ascending, 384-chunk seq-FMA -------------
// Block = 2 positions; thread t -> outputs {t, t+256}; weights read in the
// ORIGINAL layout w[o][c][tap] (contiguous in k per output row).
__global__ __launch_bounds__(256) void k_conv_blas(const float* __restrict__ feat,
                                                   const float* __restrict__ w,
                                                   const float* __restrict__ bias,
                                                   float* __restrict__ h) {
#pragma clang fp contract(off)
    __shared__ float sf[12][CIN];      // [(ky*4+kx)][c], cols 0..3 = x0-1..x0+2
    int y  = blockIdx.y;               // 0..49
    int x0 = blockIdx.x * 2;           // grid.x = 25
    int t  = threadIdx.x;

    for (int idx = t; idx < 12 * CIN; idx += 256) {
        int c  = idx & (CIN - 1);
        int rc = idx >> 11;            // 0..11
        int r  = rc >> 2, col = rc & 3;
        int yy = y + r - 1, xx = x0 + col - 1;
        float v = 0.f;
        if ((unsigned)yy < 50u && (unsigned)xx < 50u)
            v = feat[(size_t)c * NPOS + yy * 50 + xx];
        sf[rc][c] = v;
    }
    __syncthreads();

    int o0 = t, o1 = t + 256;
    const float* w0 = w + (size_t)o0 * (CIN * 9);
    const float* w1 = w + (size_t)o1 * (CIN * 9);

    float t00 = 0.f, t01 = 0.f, t10 = 0.f, t11 = 0.f;   // [o][pos]
    float c00 = 0.f, c01 = 0.f, c10 = 0.f, c11 = 0.f;
    int kc = 0;

    for (int c = 0; c < CIN; ++c) {
        const float* b0 = w0 + c * 9;
        const float* b1 = w1 + c * 9;
#pragma unroll
        for (int tap = 0; tap < 9; ++tap) {
            int r = (tap / 3) * 4 + (tap % 3);
            float x0v = sf[r][c], x1v = sf[r + 1][c];
            float wv0 = b0[tap], wv1 = b1[tap];
            c00 = fmaf(x0v, wv0, c00);
            c01 = fmaf(x1v, wv0, c01);
            c10 = fmaf(x0v, wv1, c10);
            c11 = fmaf(x1v, wv1, c11);
            if (++kc == 384) {          // 18432 = 48*384 exactly
                t00 = t00 + c00; c00 = 0.f;
                t01 = t01 + c01; c01 = 0.f;
                t10 = t10 + c10; c10 = 0.f;
                t11 = t11 + c11; c11 = 0.f;
                kc = 0;
            }
        }
    }

    float bz0 = bias[o0], bz1 = bias[o1];
    int p0 = y * 50 + x0;
    h[(size_t)p0 * CH + o0]       = fmaxf(t00 + bz0, 0.f);
    h[(size_t)(p0 + 1) * CH + o0] = fmaxf(t01 + bz0, 0.f);
    h[(size_t)p0 * CH + o1]       = fmaxf(t10 + bz1, 0.f);
    h[(size_t)(p0 + 1) * CH + o1] = fmaxf(t11 + bz1, 0.f);
}

// -------- K2: f32 head, chunks 384+128 seq-FMA, strict f32 decode ------------
__global__ __launch_bounds__(256) void k_head32(const float* __restrict__ h,
                                                const float* __restrict__ wcls,
                                                const float* __restrict__ bcls,
                                                const float* __restrict__ wreg,
                                                const float* __restrict__ breg,
                                                const void* __restrict__ imh,
                                                const void* __restrict__ imw,
                                                float* __restrict__ scores,
                                                float* __restrict__ boxes) {
#pragma clang fp contract(off)
    __shared__ float sh[CH];
    __shared__ float sm[54];
    int p = blockIdx.x;
    int t = threadIdx.x;

    for (int c = t; c < CH; c += 256) sh[c] = h[(size_t)p * CH + c];
    __syncthreads();

    if (t < 54) {
        const float* wr = (t < 18) ? (wcls + (size_t)t * CH)
                                   : (wreg + (size_t)(t - 18) * CH);
        float ch = 0.f;
        for (int c = 0; c < 384; ++c) ch = fmaf(sh[c], wr[c], ch);
        float tot = ch;
        ch = 0.f;
        for (int c = 384; c < 512; ++c) ch = fmaf(sh[c], wr[c], ch);
        tot = tot + ch;
        sm[t] = tot + ((t < 18) ? bcls[t] : breg[t - 18]);
    }
    __syncthreads();

    if (t < 9) {
        int a = t;
        float c0 = sm[a];
        float c1 = sm[9 + a];
        float mx = fmaxf(c0, c1);
        float e0 = expf(c0 - mx);
        float e1 = expf(c1 - mx);
        float sc = e1 / (e0 + e1);

        float dxv = sm[18 + a * 4 + 0];
        float dyv = sm[18 + a * 4 + 1];
        float dwv = sm[18 + a * 4 + 2];
        float dhv = sm[18 + a * 4 + 3];

        int y = p / 50, x = p % 50;
        const float sizes[3] = {128.f, 256.f, 512.f};
        const float rats[3]  = {0.5f, 1.f, 2.f};
        float sr  = sqrtf(rats[a % 3]);
        float wsf = sizes[a / 3] / sr;
        float hsf = sizes[a / 3] * sr;
        float cx = ((float)x + 0.5f) * 32.f;
        float cy = ((float)y + 0.5f) * 32.f;
        float x1 = cx - wsf / 2.f, y1 = cy - hsf / 2.f;
        float x2 = cx + wsf / 2.f, y2 = cy + hsf / 2.f;

        float aw = x2 - x1, ah = y2 - y1;
        float acx = x1 + 0.5f * aw, acy = y1 + 0.5f * ah;
        float pcx = dxv * aw + acx, pcy = dyv * ah + acy;
        float pw = expf(fminf(dwv, 4.f)) * aw;
        float ph = expf(fminf(dhv, 4.f)) * ah;
        float bx1 = pcx - pw / 2.f, by1 = pcy - ph / 2.f;
        float bx2 = pcx + pw / 2.f, by2 = pcy + ph / 2.f;
        float fw = read_dimf(imw), fh = read_dimf(imh);

        size_t n = (size_t)p * 9 + a;
        scores[n] = sc;
        float4 bx;
        bx.x = fminf(fmaxf(bx1, 0.f), fw);
        bx.y = fminf(fmaxf(by1, 0.f), fh);
        bx.z = fminf(fmaxf(bx2, 0.f), fw);
        bx.w = fminf(fmaxf(by2, 0.f), fh);
        ((float4*)boxes)[n] = bx;
    }
}

// ------------------------- K3: build sort keys -------------------------------
__global__ __launch_bounds__(256) void k_keys(const float* __restrict__ scores,
                                              unsigned long long* __restrict__ keys) {
    int t = blockIdx.x * 256 + threadIdx.x;
    int b = t >> 15, n = t & 32767;
    unsigned long long key = 0ULL;
    if (n < NANCH) {
        unsigned u = __float_as_uint(scores[(size_t)b * NANCH + n]);
        key = ((unsigned long long)u << 32) | (unsigned)(0xFFFFFFFFu - n);
    }
    keys[t] = key;
}

// ------------------------- K4: textbook bitonic sort, one block/image --------
__global__ __launch_bounds__(1024) void k_sort_img(unsigned long long* keys) {
    unsigned long long* g = keys + ((size_t)blockIdx.x << 15);
    int t = threadIdx.x;
    for (int k = 2; k <= NSORT; k <<= 1) {
        for (int j = k >> 1; j >= 1; j >>= 1) {
            for (int i = t; i < NSORT; i += 1024) {
                int l = i ^ j;
                if (l > i) {
                    unsigned long long a = g[i], b = g[l];
                    bool down = ((i & k) == 0);
                    bool sw = down ? (a < b) : (a > b);
                    if (sw) { g[i] = b; g[l] = a; }
                }
            }
            __syncthreads();
        }
    }
}

// -------------- K5: NMS, strict f32 IOU, one block per image -----------------
__global__ __launch_bounds__(256) void k_nms32(const unsigned long long* __restrict__ keys,
                                               const float* __restrict__ boxes,
                                               float* __restrict__ out) {
#pragma clang fp contract(off)
    int b = blockIdx.x;
    const unsigned long long* kb_ = keys + ((size_t)b << 15);
    const float4* bxs = (const float4*)boxes + (size_t)b * NANCH;
    __shared__ float4 sbx[PRE_NMS_K];
    __shared__ int skeep[PRE_NMS_K];
    __shared__ int slist[TOP_N];
    __shared__ int sflag;
    int t = threadIdx.x;

    for (int i = t; i < PRE_NMS_K; i += 256) {
        unsigned n = 0xFFFFFFFFu - (unsigned)(kb_[i] & 0xFFFFFFFFu);
        sbx[i] = bxs[n];
        skeep[i] = 0;
    }
    __syncthreads();

    for (int i = 0; i < PRE_NMS_K; ++i) {
        if (t == 0) sflag = 0;
        __syncthreads();
        float4 bi = sbx[i];
        float areai = (bi.z - bi.x) * (bi.w - bi.y);
        for (int j = t; j < i; j += 256) {
            if (!skeep[j]) continue;
            float4 bj = sbx[j];
            float areaj = (bj.z - bj.x) * (bj.w - bj.y);
            float lx = fmaxf(bi.x, bj.x), ly = fmaxf(bi.y, bj.y);
            float rx = fminf(bi.z, bj.z), ry = fminf(bi.w, bj.w);
            float iw = fmaxf(rx - lx, 0.f), ih = fmaxf(ry - ly, 0.f);
            float inter = iw * ih;
            float den = areai + areaj;
            den = den - inter;
            den = den + 1e-9f;
            float iou = inter / den;
            if (iou > 0.7f) sflag = 1;
        }
        __syncthreads();
        if (t == 0) skeep[i] = !sflag;
        __syncthreads();
    }

    if (t == 0) {
        int c = 0;
        for (int i = 0; i < PRE_NMS_K && c < TOP_N; ++i)
            if (skeep[i]) slist[c++] = i;
        for (int i = 0; i < PRE_NMS_K && c < TOP_N; ++i)
            if (!skeep[i]) slist[c++] = i;
    }
    __syncthreads();

    for (int r = t; r < TOP_N; r += 256) {
        int i = slist[r];
        ((float4*)out)[(size_t)b * TOP_N + r] = sbx[i];
    }
}

// ---------------------------------------------------------------------------
extern "C" void kernel_launch(void* const* d_in, const int* in_sizes, int n_in,
                              void* d_out, int out_size, void* d_ws, size_t ws_size,
                              hipStream_t stream) {
    const float* feat   = (const float*)d_in[0];
    const float* w_conv = (const float*)d_in[1];
    const float* b_conv = (const float*)d_in[2];
    const float* w_cls  = (const float*)d_in[3];
    const float* b_cls  = (const float*)d_in[4];
    const float* w_reg  = (const float*)d_in[5];
    const float* b_reg  = (const float*)d_in[6];
    const void*  img_h  = d_in[7];
    const void*  img_w  = d_in[8];

    char* ws = (char*)d_ws;
    float* h                   = (float*)(ws + 0);
    float* scores              = (float*)(ws + 5120000);
    float* boxes               = (float*)(ws + 5480000);
    unsigned long long* keys   = (unsigned long long*)(ws + 6920000);

    for (int b = 0; b < BIMG; ++b) {
        k_conv_blas<<<dim3(25, 50), 256, 0, stream>>>(
            feat + (size_t)b * CIN * NPOS, w_conv, b_conv, h);
        k_head32<<<NPOS, 256, 0, stream>>>(
            h, w_cls, b_cls, w_reg, b_reg, img_h, img_w,
            scores + (size_t)b * NANCH, boxes + (size_t)b * NANCH * 4);
    }

    k_keys<<<(BIMG * NSORT) / 256, 256, 0, stream>>>(scores, keys);
    k_sort_img<<<BIMG, 1024, 0, stream>>>(keys);
    k_nms32<<<BIMG, 256, 0, stream>>>(keys, boxes, (float*)d_out);
}

// Round 17
// 9335.906 us; speedup vs baseline: 20.2581x; 20.2581x over previous
//
#include <hip/hip_runtime.h>
#include <hip/hip_bf16.h>
#include <math.h>

// ---------------------------------------------------------------------------
// FasterRCNN RPN — PASSING semantics (round 16), optimized conv.
// Bit-exact invariants preserved:
//   conv element: k=(c*9+tap) ascending, seq-fmaf in 384-chunks, chunk sums
//   added in order, + bias, relu        (OpenBLAS sgemm kc=384 model)
//   head element: same with chunks 384+128
//   downstream: strict f32, f32-score keys w/ low-index ties, f32 IOU vs 0.7f
// Conv is now an LDS-tiled GEMM (BK=16, 64x64 tile, 4x4/thread); 384%16==0
// so chunk boundaries align with tile steps -> identical per-element sums.
// Sort: multi-kernel LDS bitonic (keys unique -> any correct sort identical).
// NMS: bitmask formulation (identical f32 IOU expression & greedy semantics).
//
// Workspace (bytes):
//   wtT    [18432][512] f32  0 .. 37,748,736
//   h      [2500][512]  f32  (per-image)  .. 42,868,736
//   scores [4][22500]   f32               .. 43,228,736
//   boxes  [4][22500][4]f32               .. 44,668,736
//   keys   [4][32768]   u64               .. 45,717,312
//   masks  [4][2000][32]u64               .. 47,765,312
// ---------------------------------------------------------------------------

#define CIN   2048
#define CH    512
#define NPOS  2500
#define NANCH 22500
#define NSORT 32768
#define BIMG  4
#define PRE_NMS_K 2000
#define TOP_N 1000
#define KWORDS 32
#define KTOT  18432
#define NKT   1152     // KTOT/16

__device__ __forceinline__ float read_dimf(const void* p) {
    int i32 = *(const int*)p;
    if (i32 >= 1 && i32 <= 1000000) return (float)i32;
    float f32 = *(const float*)p;
    if (f32 >= 1.f && f32 <= 1e6f) return f32;
    return (float)(*(const double*)p);
}

// --------- K0: wtT[(c*9+tap)*512+o] = w[(o*2048+c)*9+tap] --------------------
__global__ __launch_bounds__(256) void k_wtT(const float* __restrict__ w,
                                             float* __restrict__ wtT) {
    size_t idx = (size_t)blockIdx.x * 256 + threadIdx.x;   // 9,437,184 exact
    int o = idx & 511;
    size_t k = idx >> 9;            // c*9+tap
    int tap = (int)(k % 9);
    int c = (int)(k / 9);
    wtT[idx] = w[((size_t)o * CIN + c) * 9 + tap];
}

// --------- K1: conv GEMM, f32, 384-chunked seq-FMA (bit-exact) ---------------
__global__ __launch_bounds__(256) void k_conv_gemm(const float* __restrict__ feat,
                                                   const float* __restrict__ wtT,
                                                   const float* __restrict__ bias,
                                                   float* __restrict__ h) {
#pragma clang fp contract(off)
    __shared__ __align__(16) float As[16][64];
    __shared__ __align__(16) float Bs[16][64];
    int tid = threadIdx.x;
    int tx = tid & 15, ty = tid >> 4;
    int m0 = blockIdx.x * 64, n0 = blockIdx.y * 64;

    int i  = tid & 63;              // tile column loaded by this thread
    int kb = tid >> 6;              // base k row (0..3)
    int m  = m0 + i;
    int y0 = m / 50, x0 = m % 50;
    bool mv = (m < NPOS);

    float tot[4][4] = {};
    float chk[4][4] = {};

    for (int kt = 0; kt < NKT; ++kt) {
        int k0 = kt * 16;
        __syncthreads();
#pragma unroll
        for (int e = 0; e < 4; ++e) {
            int k = k0 + kb + e * 4;
            int c = k / 9, tap = k % 9;
            int dy = tap / 3 - 1, dx = tap % 3 - 1;
            int yy = y0 + dy, xx = x0 + dx;
            float av = 0.f;
            if (mv && (unsigned)yy < 50u && (unsigned)xx < 50u)
                av = feat[(size_t)c * NPOS + yy * 50 + xx];
            As[kb + e * 4][i] = av;
            Bs[kb + e * 4][i] = wtT[(size_t)k * CH + n0 + i];
        }
        __syncthreads();
#pragma unroll
        for (int kk = 0; kk < 16; ++kk) {
            float4 a4 = *(const float4*)&As[kk][ty * 4];
            float4 b4 = *(const float4*)&Bs[kk][tx * 4];
            float av[4] = {a4.x, a4.y, a4.z, a4.w};
            float bv[4] = {b4.x, b4.y, b4.z, b4.w};
#pragma unroll
            for (int ii = 0; ii < 4; ++ii)
#pragma unroll
                for (int jj = 0; jj < 4; ++jj)
                    chk[ii][jj] = fmaf(av[ii], bv[jj], chk[ii][jj]);
        }
        if ((kt % 24) == 23) {      // 384-element chunk boundary
#pragma unroll
            for (int ii = 0; ii < 4; ++ii)
#pragma unroll
                for (int jj = 0; jj < 4; ++jj) {
                    tot[ii][jj] = tot[ii][jj] + chk[ii][jj];
                    chk[ii][jj] = 0.f;
                }
        }
    }

#pragma unroll
    for (int ii = 0; ii < 4; ++ii) {
        int mm = m0 + ty * 4 + ii;
        if (mm >= NPOS) continue;
#pragma unroll
        for (int jj = 0; jj < 4; ++jj) {
            int n = n0 + tx * 4 + jj;
            float v = tot[ii][jj] + bias[n];
            h[(size_t)mm * CH + n] = fmaxf(v, 0.f);
        }
    }
}

// -------- K2: f32 head, chunks 384+128 seq-FMA, strict f32 decode ------------
__global__ __launch_bounds__(256) void k_head32(const float* __restrict__ h,
                                                const float* __restrict__ wcls,
                                                const float* __restrict__ bcls,
                                                const float* __restrict__ wreg,
                                                const float* __restrict__ breg,
                                                const void* __restrict__ imh,
                                                const void* __restrict__ imw,
                                                float* __restrict__ scores,
                                                float* __restrict__ boxes) {
#pragma clang fp contract(off)
    __shared__ float sh[CH];
    __shared__ float sm[54];
    int p = blockIdx.x;
    int t = threadIdx.x;

    for (int c = t; c < CH; c += 256) sh[c] = h[(size_t)p * CH + c];
    __syncthreads();

    if (t < 54) {
        const float* wr = (t < 18) ? (wcls + (size_t)t * CH)
                                   : (wreg + (size_t)(t - 18) * CH);
        float ch = 0.f;
        for (int c = 0; c < 384; ++c) ch = fmaf(sh[c], wr[c], ch);
        float tot = ch;
        ch = 0.f;
        for (int c = 384; c < 512; ++c) ch = fmaf(sh[c], wr[c], ch);
        tot = tot + ch;
        sm[t] = tot + ((t < 18) ? bcls[t] : breg[t - 18]);
    }
    __syncthreads();

    if (t < 9) {
        int a = t;
        float c0 = sm[a];
        float c1 = sm[9 + a];
        float mx = fmaxf(c0, c1);
        float e0 = expf(c0 - mx);
        float e1 = expf(c1 - mx);
        float sc = e1 / (e0 + e1);

        float dxv = sm[18 + a * 4 + 0];
        float dyv = sm[18 + a * 4 + 1];
        float dwv = sm[18 + a * 4 + 2];
        float dhv = sm[18 + a * 4 + 3];

        int y = p / 50, x = p % 50;
        const float sizes[3] = {128.f, 256.f, 512.f};
        const float rats[3]  = {0.5f, 1.f, 2.f};
        float sr  = sqrtf(rats[a % 3]);
        float wsf = sizes[a / 3] / sr;
        float hsf = sizes[a / 3] * sr;
        float cx = ((float)x + 0.5f) * 32.f;
        float cy = ((float)y + 0.5f) * 32.f;
        float x1 = cx - wsf / 2.f, y1 = cy - hsf / 2.f;
        float x2 = cx + wsf / 2.f, y2 = cy + hsf / 2.f;

        float aw = x2 - x1, ah = y2 - y1;
        float acx = x1 + 0.5f * aw, acy = y1 + 0.5f * ah;
        float pcx = dxv * aw + acx, pcy = dyv * ah + acy;
        float pw = expf(fminf(dwv, 4.f)) * aw;
        float ph = expf(fminf(dhv, 4.f)) * ah;
        float bx1 = pcx - pw / 2.f, by1 = pcy - ph / 2.f;
        float bx2 = pcx + pw / 2.f, by2 = pcy + ph / 2.f;
        float fw = read_dimf(imw), fh = read_dimf(imh);

        size_t n = (size_t)p * 9 + a;
        scores[n] = sc;
        float4 bx;
        bx.x = fminf(fmaxf(bx1, 0.f), fw);
        bx.y = fminf(fmaxf(by1, 0.f), fh);
        bx.z = fminf(fmaxf(bx2, 0.f), fw);
        bx.w = fminf(fmaxf(by2, 0.f), fh);
        ((float4*)boxes)[n] = bx;
    }
}

// ------------------------- K3: build sort keys -------------------------------
__global__ __launch_bounds__(256) void k_keys(const float* __restrict__ scores,
                                              unsigned long long* __restrict__ keys) {
    int t = blockIdx.x * 256 + threadIdx.x;
    int b = t >> 15, n = t & 32767;
    unsigned long long key = 0ULL;
    if (n < NANCH) {
        unsigned u = __float_as_uint(scores[(size_t)b * NANCH + n]);
        key = ((unsigned long long)u << 32) | (unsigned)(0xFFFFFFFFu - n);
    }
    keys[t] = key;
}

// -------------------- K4: bitonic sort (multi-kernel, descending) ------------
__device__ __forceinline__ void ce_swap(unsigned long long* s, int i, int l, bool down) {
    unsigned long long a = s[i], b = s[l];
    bool sw = down ? (a < b) : (a > b);
    if (sw) { s[i] = b; s[l] = a; }
}

__global__ __launch_bounds__(1024) void k_sort_local_full(unsigned long long* keys) {
    __shared__ unsigned long long s[2048];
    int t = threadIdx.x;
    size_t base = (size_t)blockIdx.x * 2048;
    int gbase = (blockIdx.x & 15) << 11;
    s[t] = keys[base + t]; s[t + 1024] = keys[base + t + 1024];
    __syncthreads();
    for (int k = 2; k <= 2048; k <<= 1) {
        for (int j = k >> 1; j >= 1; j >>= 1) {
            int i = ((t & ~(j - 1)) << 1) | (t & (j - 1));
            bool down = (((gbase + i) & k) == 0);
            ce_swap(s, i, i + j, down);
            __syncthreads();
        }
    }
    keys[base + t] = s[t]; keys[base + t + 1024] = s[t + 1024];
}

__global__ __launch_bounds__(1024) void k_sort_local_j(unsigned long long* keys, int k) {
    __shared__ unsigned long long s[2048];
    int t = threadIdx.x;
    size_t base = (size_t)blockIdx.x * 2048;
    int gbase = (blockIdx.x & 15) << 11;
    s[t] = keys[base + t]; s[t + 1024] = keys[base + t + 1024];
    __syncthreads();
    for (int j = 1024; j >= 1; j >>= 1) {
        int i = ((t & ~(j - 1)) << 1) | (t & (j - 1));
        bool down = (((gbase + i) & k) == 0);
        ce_swap(s, i, i + j, down);
        __syncthreads();
    }
    keys[base + t] = s[t]; keys[base + t + 1024] = s[t + 1024];
}

__global__ __launch_bounds__(256) void k_sort_gstep(unsigned long long* keys, int k, int j) {
    int t = blockIdx.x * 256 + threadIdx.x;
    int b = t >> 14, u = t & 16383;
    int i = ((u & ~(j - 1)) << 1) | (u & (j - 1));
    unsigned long long* g = keys + ((size_t)b << 15);
    bool down = ((i & k) == 0);
    unsigned long long a = g[i], bb = g[i + j];
    bool sw = down ? (a < bb) : (a > bb);
    if (sw) { g[i] = bb; g[i + j] = a; }
}

// ---------------- K5: IOU bitmasks, strict f32 (reference expr) --------------
__global__ __launch_bounds__(256) void k_masks(const unsigned long long* __restrict__ keys,
                                               const float* __restrict__ boxes,
                                               unsigned long long* __restrict__ masks) {
#pragma clang fp contract(off)
    int w = blockIdx.x & 31, b = blockIdx.x >> 5;
    __shared__ float4 jb[64];
    int t = threadIdx.x;
    const unsigned long long* kb_ = keys + ((size_t)b << 15);
    const float4* bxs = (const float4*)boxes + (size_t)b * NANCH;

    if (t < 64) {
        int j = w * 64 + t;
        float4 v = make_float4(0.f, 0.f, 0.f, 0.f);
        if (j < PRE_NMS_K) {
            unsigned n = 0xFFFFFFFFu - (unsigned)(kb_[j] & 0xFFFFFFFFu);
            v = bxs[n];
        }
        jb[t] = v;
    }
    __syncthreads();

    for (int i = t; i < PRE_NMS_K; i += 256) {
        unsigned ni = 0xFFFFFFFFu - (unsigned)(kb_[i] & 0xFFFFFFFFu);
        float4 bi = bxs[ni];
        float areai = (bi.z - bi.x) * (bi.w - bi.y);
        unsigned long long m = 0ULL;
        for (int bit = 0; bit < 64; ++bit) {
            int j = w * 64 + bit;
            if (j >= PRE_NMS_K || j == i) continue;
            float4 bj = jb[bit];
            float areaj = (bj.z - bj.x) * (bj.w - bj.y);
            float lx = fmaxf(bi.x, bj.x), ly = fmaxf(bi.y, bj.y);
            float rx = fminf(bi.z, bj.z), ry = fminf(bi.w, bj.w);
            float iw = fmaxf(rx - lx, 0.f), ih = fmaxf(ry - ly, 0.f);
            float inter = iw * ih;
            float den = areai + areaj;
            den = den - inter;
            den = den + 1e-9f;
            float iou = inter / den;
            if (iou > 0.7f) m |= (1ULL << bit);
        }
        masks[((size_t)b * PRE_NMS_K + i) * KWORDS + w] = m;
    }
}

// ---------------- K6: greedy NMS (bitmask) + select + f32 output -------------
__global__ __launch_bounds__(64) void k_nms(const unsigned long long* __restrict__ keys,
                                            const float* __restrict__ boxes,
                                            const unsigned long long* __restrict__ masks,
                                            float* __restrict__ out) {
    int b = blockIdx.x;
    int lane = threadIdx.x;
    const unsigned long long* mrow = masks + (size_t)b * PRE_NMS_K * KWORDS;
    const unsigned long long* kb_ = keys + ((size_t)b << 15);
    const float4* bxs = (const float4*)boxes + (size_t)b * NANCH;

    unsigned long long keep = 0ULL;   // lane l (<32) holds keep word l
    unsigned long long nextw = (lane < KWORDS) ? mrow[lane] : 0ULL;
    for (int i = 0; i < PRE_NMS_K; ++i) {
        unsigned long long mw = nextw;
        if (i + 1 < PRE_NMS_K)
            nextw = (lane < KWORDS) ? mrow[(size_t)(i + 1) * KWORDS + lane] : 0ULL;
        bool sup = __any((mw & keep) != 0ULL);
        if (!sup && lane == (i >> 6)) keep |= 1ULL << (i & 63);
    }

    __shared__ unsigned long long keepw[KWORDS];
    __shared__ int slist[TOP_N];
    if (lane < KWORDS) keepw[lane] = keep;
    __syncthreads();

    if (lane == 0) {
        int c = 0;
        for (int i = 0; i < PRE_NMS_K && c < TOP_N; ++i)
            if ((keepw[i >> 6] >> (i & 63)) & 1ULL) slist[c++] = i;
        for (int i = 0; i < PRE_NMS_K && c < TOP_N; ++i)
            if (!((keepw[i >> 6] >> (i & 63)) & 1ULL)) slist[c++] = i;
    }
    __syncthreads();

    for (int r = lane; r < TOP_N; r += 64) {
        int i = slist[r];
        unsigned n = 0xFFFFFFFFu - (unsigned)(kb_[i] & 0xFFFFFFFFu);
        ((float4*)out)[(size_t)b * TOP_N + r] = bxs[n];
    }
}

// ---------------------------------------------------------------------------
extern "C" void kernel_launch(void* const* d_in, const int* in_sizes, int n_in,
                              void* d_out, int out_size, void* d_ws, size_t ws_size,
                              hipStream_t stream) {
    const float* feat   = (const float*)d_in[0];
    const float* w_conv = (const float*)d_in[1];
    const float* b_conv = (const float*)d_in[2];
    const float* w_cls  = (const float*)d_in[3];
    const float* b_cls  = (const float*)d_in[4];
    const float* w_reg  = (const float*)d_in[5];
    const float* b_reg  = (const float*)d_in[6];
    const void*  img_h  = d_in[7];
    const void*  img_w  = d_in[8];

    char* ws = (char*)d_ws;
    float* wtT                 = (float*)(ws + 0);
    float* h                   = (float*)(ws + 37748736);
    float* scores              = (float*)(ws + 42868736);
    float* boxes               = (float*)(ws + 43228736);
    unsigned long long* keys   = (unsigned long long*)(ws + 44668736);
    unsigned long long* masks  = (unsigned long long*)(ws + 45717312);

    k_wtT<<<(KTOT * CH) / 256, 256, 0, stream>>>(w_conv, wtT);

    for (int b = 0; b < BIMG; ++b) {
        k_conv_gemm<<<dim3(40, CH / 64), 256, 0, stream>>>(
            feat + (size_t)b * CIN * NPOS, wtT, b_conv, h);
        k_head32<<<NPOS, 256, 0, stream>>>(
            h, w_cls, b_cls, w_reg, b_reg, img_h, img_w,
            scores + (size_t)b * NANCH, boxes + (size_t)b * NANCH * 4);
    }

    k_keys<<<(BIMG * NSORT) / 256, 256, 0, stream>>>(scores, keys);

    k_sort_local_full<<<BIMG * (NSORT / 2048), 1024, 0, stream>>>(keys);
    for (int k = 4096; k <= NSORT; k <<= 1) {
        for (int j = k >> 1; j >= 2048; j >>= 1)
            k_sort_gstep<<<(BIMG * NSORT / 2) / 256, 256, 0, stream>>>(keys, k, j);
        k_sort_local_j<<<BIMG * (NSORT / 2048), 1024, 0, stream>>>(keys, k);
    }

    k_masks<<<BIMG * KWORDS, 256, 0, stream>>>(keys, boxes, masks);
    k_nms<<<BIMG, 64, 0, stream>>>(keys, boxes, masks, (float*)d_out);
}

// Round 18
// 4998.383 us; speedup vs baseline: 37.8378x; 1.8678x over previous
//
#include <hip/hip_runtime.h>
#include <hip/hip_bf16.h>
#include <math.h>

// ---------------------------------------------------------------------------
// FasterRCNN RPN — PASSING semantics (round 16/17), conv occupancy fix.
// Bit-exact invariants preserved:
//   conv element: k=(c*9+tap) ascending, seq-fmaf in 384-chunks, chunk sums
//   added in order, + bias, relu        (OpenBLAS sgemm kc=384 model)
//   head element: same with chunks 384+128
//   downstream: strict f32, f32-score keys w/ low-index ties, f32 IOU vs 0.7f
// Changes vs round 17 (all layout/parallelism only):
//   * conv batched over images (grid.z=4): 320 -> 1280 blocks
//   * BK 16 -> 32 (chunk 384 = 12*32 aligns; identical per-element sums)
//   * head batched over images (grid (2500,4))
//
// Workspace (bytes)  [= round-0 verified footprint 63,125,312]:
//   wtT    [18432][512]   f32  0 .. 37,748,736
//   h      [4][2500][512] f32  .. 58,228,736
//   scores [4][22500]     f32  .. 58,588,736
//   boxes  [4][22500][4]  f32  .. 60,028,736
//   keys   [4][32768]     u64  .. 61,077,312
//   masks  [4][2000][32]  u64  .. 63,125,312
// ---------------------------------------------------------------------------

#define CIN   2048
#define CH    512
#define NPOS  2500
#define NANCH 22500
#define NSORT 32768
#define BIMG  4
#define PRE_NMS_K 2000
#define TOP_N 1000
#define KWORDS 32
#define KTOT  18432
#define BK    32
#define NKT32 576      // KTOT/32

__device__ __forceinline__ float read_dimf(const void* p) {
    int i32 = *(const int*)p;
    if (i32 >= 1 && i32 <= 1000000) return (float)i32;
    float f32 = *(const float*)p;
    if (f32 >= 1.f && f32 <= 1e6f) return f32;
    return (float)(*(const double*)p);
}

// --------- K0: wtT[(c*9+tap)*512+o] = w[(o*2048+c)*9+tap] --------------------
__global__ __launch_bounds__(256) void k_wtT(const float* __restrict__ w,
                                             float* __restrict__ wtT) {
    size_t idx = (size_t)blockIdx.x * 256 + threadIdx.x;   // 9,437,184 exact
    int o = idx & 511;
    size_t k = idx >> 9;            // c*9+tap
    int tap = (int)(k % 9);
    int c = (int)(k / 9);
    wtT[idx] = w[((size_t)o * CIN + c) * 9 + tap];
}

// --------- K1: conv GEMM, f32, 384-chunked seq-FMA, batched images -----------
__global__ __launch_bounds__(256) void k_conv_gemm(const float* __restrict__ feat0,
                                                   const float* __restrict__ wtT,
                                                   const float* __restrict__ bias,
                                                   float* __restrict__ h) {
#pragma clang fp contract(off)
    __shared__ __align__(16) float As[BK][64];
    __shared__ __align__(16) float Bs[BK][64];
    int tid = threadIdx.x;
    int tx = tid & 15, ty = tid >> 4;
    int m0 = blockIdx.x * 64, n0 = blockIdx.y * 64;
    int b  = blockIdx.z;
    const float* feat = feat0 + (size_t)b * CIN * NPOS;

    int i  = tid & 63;              // tile column loaded by this thread
    int kb = tid >> 6;              // base k row (0..3)
    int m  = m0 + i;
    int y0 = m / 50, x0 = m % 50;
    bool mv = (m < NPOS);

    float tot[4][4] = {};
    float chk[4][4] = {};

    for (int kt = 0; kt < NKT32; ++kt) {
        int k0 = kt * BK;
        __syncthreads();
#pragma unroll
        for (int e = 0; e < 8; ++e) {
            int kr = kb + e * 4;           // 0..31
            int k = k0 + kr;
            int c = k / 9, tap = k - c * 9;
            int dy = tap / 3 - 1, dx = tap % 3 - 1;
            int yy = y0 + dy, xx = x0 + dx;
            float av = 0.f;
            if (mv && (unsigned)yy < 50u && (unsigned)xx < 50u)
                av = feat[(size_t)c * NPOS + yy * 50 + xx];
            As[kr][i] = av;
            Bs[kr][i] = wtT[(size_t)k * CH + n0 + i];
        }
        __syncthreads();
#pragma unroll
        for (int kk = 0; kk < BK; ++kk) {
            float4 a4 = *(const float4*)&As[kk][ty * 4];
            float4 b4 = *(const float4*)&Bs[kk][tx * 4];
            float av[4] = {a4.x, a4.y, a4.z, a4.w};
            float bv[4] = {b4.x, b4.y, b4.z, b4.w};
#pragma unroll
            for (int ii = 0; ii < 4; ++ii)
#pragma unroll
                for (int jj = 0; jj < 4; ++jj)
                    chk[ii][jj] = fmaf(av[ii], bv[jj], chk[ii][jj]);
        }
        if ((kt % 12) == 11) {      // 384-element chunk boundary (12*32)
#pragma unroll
            for (int ii = 0; ii < 4; ++ii)
#pragma unroll
                for (int jj = 0; jj < 4; ++jj) {
                    tot[ii][jj] = tot[ii][jj] + chk[ii][jj];
                    chk[ii][jj] = 0.f;
                }
        }
    }

#pragma unroll
    for (int ii = 0; ii < 4; ++ii) {
        int mm = m0 + ty * 4 + ii;
        if (mm >= NPOS) continue;
#pragma unroll
        for (int jj = 0; jj < 4; ++jj) {
            int n = n0 + tx * 4 + jj;
            float v = tot[ii][jj] + bias[n];
            h[((size_t)b * NPOS + mm) * CH + n] = fmaxf(v, 0.f);
        }
    }
}

// -------- K2: f32 head, chunks 384+128 seq-FMA, strict f32 decode ------------
__global__ __launch_bounds__(256) void k_head32(const float* __restrict__ h,
                                                const float* __restrict__ wcls,
                                                const float* __restrict__ bcls,
                                                const float* __restrict__ wreg,
                                                const float* __restrict__ breg,
                                                const void* __restrict__ imh,
                                                const void* __restrict__ imw,
                                                float* __restrict__ scores,
                                                float* __restrict__ boxes) {
#pragma clang fp contract(off)
    __shared__ float sh[CH];
    __shared__ float sm[54];
    int p = blockIdx.x;
    int b = blockIdx.y;
    int t = threadIdx.x;

    for (int c = t; c < CH; c += 256)
        sh[c] = h[((size_t)b * NPOS + p) * CH + c];
    __syncthreads();

    if (t < 54) {
        const float* wr = (t < 18) ? (wcls + (size_t)t * CH)
                                   : (wreg + (size_t)(t - 18) * CH);
        float ch = 0.f;
        for (int c = 0; c < 384; ++c) ch = fmaf(sh[c], wr[c], ch);
        float tot = ch;
        ch = 0.f;
        for (int c = 384; c < 512; ++c) ch = fmaf(sh[c], wr[c], ch);
        tot = tot + ch;
        sm[t] = tot + ((t < 18) ? bcls[t] : breg[t - 18]);
    }
    __syncthreads();

    if (t < 9) {
        int a = t;
        float c0 = sm[a];
        float c1 = sm[9 + a];
        float mx = fmaxf(c0, c1);
        float e0 = expf(c0 - mx);
        float e1 = expf(c1 - mx);
        float sc = e1 / (e0 + e1);

        float dxv = sm[18 + a * 4 + 0];
        float dyv = sm[18 + a * 4 + 1];
        float dwv = sm[18 + a * 4 + 2];
        float dhv = sm[18 + a * 4 + 3];

        int y = p / 50, x = p % 50;
        const float sizes[3] = {128.f, 256.f, 512.f};
        const float rats[3]  = {0.5f, 1.f, 2.f};
        float sr  = sqrtf(rats[a % 3]);
        float wsf = sizes[a / 3] / sr;
        float hsf = sizes[a / 3] * sr;
        float cx = ((float)x + 0.5f) * 32.f;
        float cy = ((float)y + 0.5f) * 32.f;
        float x1 = cx - wsf / 2.f, y1 = cy - hsf / 2.f;
        float x2 = cx + wsf / 2.f, y2 = cy + hsf / 2.f;

        float aw = x2 - x1, ah = y2 - y1;
        float acx = x1 + 0.5f * aw, acy = y1 + 0.5f * ah;
        float pcx = dxv * aw + acx, pcy = dyv * ah + acy;
        float pw = expf(fminf(dwv, 4.f)) * aw;
        float ph = expf(fminf(dhv, 4.f)) * ah;
        float bx1 = pcx - pw / 2.f, by1 = pcy - ph / 2.f;
        float bx2 = pcx + pw / 2.f, by2 = pcy + ph / 2.f;
        float fw = read_dimf(imw), fh = read_dimf(imh);

        size_t n = (size_t)b * NANCH + (size_t)p * 9 + a;
        scores[n] = sc;
        float4 bx;
        bx.x = fminf(fmaxf(bx1, 0.f), fw);
        bx.y = fminf(fmaxf(by1, 0.f), fh);
        bx.z = fminf(fmaxf(bx2, 0.f), fw);
        bx.w = fminf(fmaxf(by2, 0.f), fh);
        ((float4*)boxes)[n] = bx;
    }
}

// ------------------------- K3: build sort keys -------------------------------
__global__ __launch_bounds__(256) void k_keys(const float* __restrict__ scores,
                                              unsigned long long* __restrict__ keys) {
    int t = blockIdx.x * 256 + threadIdx.x;
    int b = t >> 15, n = t & 32767;
    unsigned long long key = 0ULL;
    if (n < NANCH) {
        unsigned u = __float_as_uint(scores[(size_t)b * NANCH + n]);
        key = ((unsigned long long)u << 32) | (unsigned)(0xFFFFFFFFu - n);
    }
    keys[t] = key;
}

// -------------------- K4: bitonic sort (multi-kernel, descending) ------------
__device__ __forceinline__ void ce_swap(unsigned long long* s, int i, int l, bool down) {
    unsigned long long a = s[i], b = s[l];
    bool sw = down ? (a < b) : (a > b);
    if (sw) { s[i] = b; s[l] = a; }
}

__global__ __launch_bounds__(1024) void k_sort_local_full(unsigned long long* keys) {
    __shared__ unsigned long long s[2048];
    int t = threadIdx.x;
    size_t base = (size_t)blockIdx.x * 2048;
    int gbase = (blockIdx.x & 15) << 11;
    s[t] = keys[base + t]; s[t + 1024] = keys[base + t + 1024];
    __syncthreads();
    for (int k = 2; k <= 2048; k <<= 1) {
        for (int j = k >> 1; j >= 1; j >>= 1) {
            int i = ((t & ~(j - 1)) << 1) | (t & (j - 1));
            bool down = (((gbase + i) & k) == 0);
            ce_swap(s, i, i + j, down);
            __syncthreads();
        }
    }
    keys[base + t] = s[t]; keys[base + t + 1024] = s[t + 1024];
}

__global__ __launch_bounds__(1024) void k_sort_local_j(unsigned long long* keys, int k) {
    __shared__ unsigned long long s[2048];
    int t = threadIdx.x;
    size_t base = (size_t)blockIdx.x * 2048;
    int gbase = (blockIdx.x & 15) << 11;
    s[t] = keys[base + t]; s[t + 1024] = keys[base + t + 1024];
    __syncthreads();
    for (int j = 1024; j >= 1; j >>= 1) {
        int i = ((t & ~(j - 1)) << 1) | (t & (j - 1));
        bool down = (((gbase + i) & k) == 0);
        ce_swap(s, i, i + j, down);
        __syncthreads();
    }
    keys[base + t] = s[t]; keys[base + t + 1024] = s[t + 1024];
}

__global__ __launch_bounds__(256) void k_sort_gstep(unsigned long long* keys, int k, int j) {
    int t = blockIdx.x * 256 + threadIdx.x;
    int b = t >> 14, u = t & 16383;
    int i = ((u & ~(j - 1)) << 1) | (u & (j - 1));
    unsigned long long* g = keys + ((size_t)b << 15);
    bool down = ((i & k) == 0);
    unsigned long long a = g[i], bb = g[i + j];
    bool sw = down ? (a < bb) : (a > bb);
    if (sw) { g[i] = bb; g[i + j] = a; }
}

// ---------------- K5: IOU bitmasks, strict f32 (reference expr) --------------
__global__ __launch_bounds__(256) void k_masks(const unsigned long long* __restrict__ keys,
                                               const float* __restrict__ boxes,
                                               unsigned long long* __restrict__ masks) {
#pragma clang fp contract(off)
    int w = blockIdx.x & 31, b = blockIdx.x >> 5;
    __shared__ float4 jb[64];
    int t = threadIdx.x;
    const unsigned long long* kb_ = keys + ((size_t)b << 15);
    const float4* bxs = (const float4*)boxes + (size_t)b * NANCH;

    if (t < 64) {
        int j = w * 64 + t;
        float4 v = make_float4(0.f, 0.f, 0.f, 0.f);
        if (j < PRE_NMS_K) {
            unsigned n = 0xFFFFFFFFu - (unsigned)(kb_[j] & 0xFFFFFFFFu);
            v = bxs[n];
        }
        jb[t] = v;
    }
    __syncthreads();

    for (int i = t; i < PRE_NMS_K; i += 256) {
        unsigned ni = 0xFFFFFFFFu - (unsigned)(kb_[i] & 0xFFFFFFFFu);
        float4 bi = bxs[ni];
        float areai = (bi.z - bi.x) * (bi.w - bi.y);
        unsigned long long m = 0ULL;
        for (int bit = 0; bit < 64; ++bit) {
            int j = w * 64 + bit;
            if (j >= PRE_NMS_K || j == i) continue;
            float4 bj = jb[bit];
            float areaj = (bj.z - bj.x) * (bj.w - bj.y);
            float lx = fmaxf(bi.x, bj.x), ly = fmaxf(bi.y, bj.y);
            float rx = fminf(bi.z, bj.z), ry = fminf(bi.w, bj.w);
            float iw = fmaxf(rx - lx, 0.f), ih = fmaxf(ry - ly, 0.f);
            float inter = iw * ih;
            float den = areai + areaj;
            den = den - inter;
            den = den + 1e-9f;
            float iou = inter / den;
            if (iou > 0.7f) m |= (1ULL << bit);
        }
        masks[((size_t)b * PRE_NMS_K + i) * KWORDS + w] = m;
    }
}

// ---------------- K6: greedy NMS (bitmask) + select + f32 output -------------
__global__ __launch_bounds__(64) void k_nms(const unsigned long long* __restrict__ keys,
                                            const float* __restrict__ boxes,
                                            const unsigned long long* __restrict__ masks,
                                            float* __restrict__ out) {
    int b = blockIdx.x;
    int lane = threadIdx.x;
    const unsigned long long* mrow = masks + (size_t)b * PRE_NMS_K * KWORDS;
    const unsigned long long* kb_ = keys + ((size_t)b << 15);
    const float4* bxs = (const float4*)boxes + (size_t)b * NANCH;

    unsigned long long keep = 0ULL;   // lane l (<32) holds keep word l
    unsigned long long nextw = (lane < KWORDS) ? mrow[lane] : 0ULL;
    for (int i = 0; i < PRE_NMS_K; ++i) {
        unsigned long long mw = nextw;
        if (i + 1 < PRE_NMS_K)
            nextw = (lane < KWORDS) ? mrow[(size_t)(i + 1) * KWORDS + lane] : 0ULL;
        bool sup = __any((mw & keep) != 0ULL);
        if (!sup && lane == (i >> 6)) keep |= 1ULL << (i & 63);
    }

    __shared__ unsigned long long keepw[KWORDS];
    __shared__ int slist[TOP_N];
    if (lane < KWORDS) keepw[lane] = keep;
    __syncthreads();

    if (lane == 0) {
        int c = 0;
        for (int i = 0; i < PRE_NMS_K && c < TOP_N; ++i)
            if ((keepw[i >> 6] >> (i & 63)) & 1ULL) slist[c++] = i;
        for (int i = 0; i < PRE_NMS_K && c < TOP_N; ++i)
            if (!((keepw[i >> 6] >> (i & 63)) & 1ULL)) slist[c++] = i;
    }
    __syncthreads();

    for (int r = lane; r < TOP_N; r += 64) {
        int i = slist[r];
        unsigned n = 0xFFFFFFFFu - (unsigned)(kb_[i] & 0xFFFFFFFFu);
        ((float4*)out)[(size_t)b * TOP_N + r] = bxs[n];
    }
}

// ---------------------------------------------------------------------------
extern "C" void kernel_launch(void* const* d_in, const int* in_sizes, int n_in,
                              void* d_out, int out_size, void* d_ws, size_t ws_size,
                              hipStream_t stream) {
    const float* feat   = (const float*)d_in[0];
    const float* w_conv = (const float*)d_in[1];
    const float* b_conv = (const float*)d_in[2];
    const float* w_cls  = (const float*)d_in[3];
    const float* b_cls  = (const float*)d_in[4];
    const float* w_reg  = (const float*)d_in[5];
    const float* b_reg  = (const float*)d_in[6];
    const void*  img_h  = d_in[7];
    const void*  img_w  = d_in[8];

    char* ws = (char*)d_ws;
    float* wtT                 = (float*)(ws + 0);
    float* h                   = (float*)(ws + 37748736);
    float* scores              = (float*)(ws + 58228736);
    float* boxes               = (float*)(ws + 58588736);
    unsigned long long* keys   = (unsigned long long*)(ws + 60028736);
    unsigned long long* masks  = (unsigned long long*)(ws + 61077312);

    k_wtT<<<(KTOT * CH) / 256, 256, 0, stream>>>(w_conv, wtT);

    // Batched conv: 40 x 8 x 4 = 1280 blocks
    k_conv_gemm<<<dim3(40, CH / 64, BIMG), 256, 0, stream>>>(feat, wtT, b_conv, h);

    // Batched head: 2500 x 4 blocks
    k_head32<<<dim3(NPOS, BIMG), 256, 0, stream>>>(
        h, w_cls, b_cls, w_reg, b_reg, img_h, img_w, scores, boxes);

    k_keys<<<(BIMG * NSORT) / 256, 256, 0, stream>>>(scores, keys);

    k_sort_local_full<<<BIMG * (NSORT / 2048), 1024, 0, stream>>>(keys);
    for (int k = 4096; k <= NSORT; k <<= 1) {
        for (int j = k >> 1; j >= 2048; j >>= 1)
            k_sort_gstep<<<(BIMG * NSORT / 2) / 256, 256, 0, stream>>>(keys, k, j);
        k_sort_local_j<<<BIMG * (NSORT / 2048), 1024, 0, stream>>>(keys, k);
    }

    k_masks<<<BIMG * KWORDS, 256, 0, stream>>>(keys, boxes, masks);
    k_nms<<<BIMG, 64, 0, stream>>>(keys, boxes, masks, (float*)d_out);
}